// Round 7
// baseline (432.240 us; speedup 1.0000x reference)
//
#include <hip/hip_runtime.h>
#include <hip/hip_bf16.h>
#include <math.h>

#define NH 14
#define NKV 2
#define HD 64
#define HID 896
#define SEQ 2048
#define BATCH 2

typedef __attribute__((ext_vector_type(8))) short short8;
typedef __attribute__((ext_vector_type(4))) short short4v;
typedef __attribute__((ext_vector_type(4))) float f32x4;
typedef __attribute__((ext_vector_type(4))) _Float16 half4;
typedef unsigned short ushort_t;

__device__ __forceinline__ unsigned short f2b(float f) {
    unsigned int u = __float_as_uint(f);
    unsigned int r = (u + 0x7fffu + ((u >> 16) & 1u)) >> 16;   // RNE
    return (unsigned short)r;
}

// ---------------------------------------------------------------------------
// Prep A: X fp32 [4096,896] -> bf16 same layout. 8 elems/thread.
// ---------------------------------------------------------------------------
__global__ __launch_bounds__(256) void xcast_kernel(
    const float* __restrict__ X, ushort_t* __restrict__ Xb)
{
    size_t i = ((size_t)blockIdx.x * 256 + threadIdx.x) * 8;
    float4 a = *(const float4*)(X + i);
    float4 b = *(const float4*)(X + i + 4);
    short8 o;
    o[0] = f2b(a.x); o[1] = f2b(a.y); o[2] = f2b(a.z); o[3] = f2b(a.w);
    o[4] = f2b(b.x); o[5] = f2b(b.y); o[6] = f2b(b.z); o[7] = f2b(b.w);
    *(short8*)(Xb + i) = o;
}

// ---------------------------------------------------------------------------
// Prep B: weight transpose+cast. W [896][N] fp32 -> WT [n][k] bf16.
// ---------------------------------------------------------------------------
__global__ __launch_bounds__(256) void wtrans_kernel(
    const float* __restrict__ Wq, const float* __restrict__ Wk,
    const float* __restrict__ Wv, const float* __restrict__ Wo,
    ushort_t* __restrict__ WqkvT, ushort_t* __restrict__ WoT)
{
    __shared__ float tile[32][33];
    const int tx = threadIdx.x, ty = threadIdx.y;   // block (32,8)
    const int z = blockIdx.z;
    const float* src; ushort_t* dst; int N, rowoff;
    if      (z == 0) { src = Wq; dst = WqkvT; N = HID; rowoff = 0;    }
    else if (z == 1) { src = Wk; dst = WqkvT; N = 128; rowoff = 896;  }
    else if (z == 2) { src = Wv; dst = WqkvT; N = 128; rowoff = 1024; }
    else             { src = Wo; dst = WoT;   N = HID; rowoff = 0;    }
    const int k0 = blockIdx.x * 32;
    const int n0 = blockIdx.y * 32;
    if (n0 >= N) return;
    #pragma unroll
    for (int i = 0; i < 4; ++i)
        tile[ty * 4 + i][tx] = src[(size_t)(k0 + ty * 4 + i) * N + n0 + tx];
    __syncthreads();
    #pragma unroll
    for (int i = 0; i < 4; ++i)
        dst[(size_t)(rowoff + n0 + ty * 4 + i) * HID + k0 + tx]
            = f2b(tile[tx][ty * 4 + i]);
}

// ---------------------------------------------------------------------------
// Kernel 1: QKV GEMM via bf16 MFMA + bias + RoPE epilogue.
// q pre-scaled by 1/8. V stored f16 transposed [d][s].
// ---------------------------------------------------------------------------
#define LDA 40
__global__ __launch_bounds__(256) void qkv_kernel(
    const ushort_t* __restrict__ Xb, const ushort_t* __restrict__ WqkvT,
    const float* __restrict__ bq, const float* __restrict__ bk,
    const float* __restrict__ bv,
    ushort_t* __restrict__ qbuf, ushort_t* __restrict__ kbuf,
    _Float16* __restrict__ vbuf)
{
    __shared__ ushort_t Asb[128 * LDA];
    __shared__ ushort_t Bsb[64 * LDA];
    const int tid  = threadIdx.x;
    const int w    = tid >> 6;
    const int lane = tid & 63;
    const int quad = lane >> 4;
    const int l16  = lane & 15;
    const int m0 = blockIdx.x * 128;
    const int nt = blockIdx.y;
    const int nb = nt * 64;

    f32x4 acc[2][4];
    #pragma unroll
    for (int mf = 0; mf < 2; ++mf)
        #pragma unroll
        for (int nf = 0; nf < 4; ++nf) acc[mf][nf] = (f32x4){0.f, 0.f, 0.f, 0.f};

    for (int k0 = 0; k0 < HID; k0 += 32) {
        #pragma unroll
        for (int j = 0; j < 2; ++j) {
            int u = tid + j * 256;
            int row = u >> 2, c8 = u & 3;
            *(short8*)&Asb[row * LDA + c8 * 8] =
                *(const short8*)(Xb + (size_t)(m0 + row) * HID + k0 + c8 * 8);
        }
        {
            int row = tid >> 2, c8 = tid & 3;
            *(short8*)&Bsb[row * LDA + c8 * 8] =
                *(const short8*)(WqkvT + (size_t)(nb + row) * HID + k0 + c8 * 8);
        }
        __syncthreads();
        const ushort_t* Ab = &Asb[(w * 32 + l16) * LDA + quad * 8];
        short8 a0 = *(const short8*)Ab;
        short8 a1 = *(const short8*)(Ab + 16 * LDA);
        #pragma unroll
        for (int nf = 0; nf < 4; ++nf) {
            short8 bf = *(const short8*)&Bsb[(nf * 16 + l16) * LDA + quad * 8];
            acc[0][nf] = __builtin_amdgcn_mfma_f32_16x16x32_bf16(a0, bf, acc[0][nf], 0, 0, 0);
            acc[1][nf] = __builtin_amdgcn_mfma_f32_16x16x32_bf16(a1, bf, acc[1][nf], 0, 0, 0);
        }
        __syncthreads();
    }

    float bcol[4];
    #pragma unroll
    for (int f = 0; f < 4; ++f) {
        int d = f * 16 + l16;
        bcol[f] = (nt < 14) ? bq[nt * 64 + d]
                : (nt < 16) ? bk[(nt - 14) * 64 + d]
                            : bv[(nt - 16) * 64 + d];
    }
    const float lnth = 13.815510558f;  // ln(1e6)
    float if0 = expf(-((float)l16)        / 32.0f * lnth);
    float if1 = expf(-((float)(l16 + 16)) / 32.0f * lnth);

    #pragma unroll
    for (int mf = 0; mf < 2; ++mf)
        #pragma unroll
        for (int r = 0; r < 4; ++r) {
            int grow = m0 + w * 32 + mf * 16 + quad * 4 + r;
            int b = grow >> 11;
            int s = grow & 2047;
            float v0 = acc[mf][0][r] + bcol[0];
            float v1 = acc[mf][1][r] + bcol[1];
            float v2 = acc[mf][2][r] + bcol[2];
            float v3 = acc[mf][3][r] + bcol[3];
            if (nt < 16) {
                float s0, c0, s1, c1;
                sincosf((float)s * if0, &s0, &c0);
                sincosf((float)s * if1, &s1, &c1);
                float n0 = v0 * c0 - v2 * s0;
                float n2 = v2 * c0 + v0 * s0;
                float n1 = v1 * c1 - v3 * s1;
                float n3 = v3 * c1 + v1 * s1;
                v0 = n0; v1 = n1; v2 = n2; v3 = n3;
            }
            if (nt < 14) {
                ushort_t* dst = qbuf + ((size_t)(b * NH + nt) * SEQ + s) * HD;
                dst[l16]      = f2b(v0 * 0.125f);
                dst[l16 + 16] = f2b(v1 * 0.125f);
                dst[l16 + 32] = f2b(v2 * 0.125f);
                dst[l16 + 48] = f2b(v3 * 0.125f);
            } else if (nt < 16) {
                ushort_t* dst = kbuf + ((size_t)(b * NKV + nt - 14) * SEQ + s) * HD;
                dst[l16]      = f2b(v0);
                dst[l16 + 16] = f2b(v1);
                dst[l16 + 32] = f2b(v2);
                dst[l16 + 48] = f2b(v3);
            } else {
                _Float16* dst = vbuf + (size_t)(b * NKV + nt - 16) * HD * SEQ + s;
                dst[(size_t)(l16)      * SEQ] = (_Float16)v0;
                dst[(size_t)(l16 + 16) * SEQ] = (_Float16)v1;
                dst[(size_t)(l16 + 32) * SEQ] = (_Float16)v2;
                dst[(size_t)(l16 + 48) * SEQ] = (_Float16)v3;
            }
        }
}

// ---------------------------------------------------------------------------
// Kernel 2: causal flash attention — barrier-free, LDS-free, one wave per
// 16 q-rows. grid (128, NH, B), block 64. g = 127-bx (longest first);
// q-rows g*16..+15; key tiles kt = 0..g>>2. S^T = mfma(K-frag, Q-frag) with
// K/V fragments loaded straight from global (L1/L2-resident, 512 KB per
// (b,kvh)). No __syncthreads at all: 3584 independent waves hide latency.
// Softmax: 2 shuffles per tile (xor16/32). PV: f16 16x16x16, P^T already in
// B-operand layout.
// ---------------------------------------------------------------------------
__global__ __launch_bounds__(64) void attn_kernel(
    const ushort_t* __restrict__ qbuf, const ushort_t* __restrict__ kbuf,
    const _Float16* __restrict__ vbuf, ushort_t* __restrict__ abuf)
{
    const int lane = threadIdx.x;
    const int quad = lane >> 4;
    const int l16  = lane & 15;
    const int g  = 127 - blockIdx.x;         // 16-row group, longest first
    const int h  = blockIdx.y;
    const int b  = blockIdx.z;
    const int kvh = h / (NH / NKV);
    const int qt  = g >> 2;                  // last key-tile index
    const int sub = g & 3;                   // 16-row slot within 64-key tile
    const int rowl = sub * 16 + l16;         // local row for diag masking

    const ushort_t* kb_h = kbuf + (size_t)(b * NKV + kvh) * SEQ * HD;
    const _Float16* vt_h = vbuf + (size_t)(b * NKV + kvh) * HD * SEQ;

    const ushort_t* qrow =
        qbuf + ((size_t)((b * NH + h) * SEQ) + g * 16 + l16) * HD;
    short8 qf0 = *(const short8*)(qrow + quad * 8);
    short8 qf1 = *(const short8*)(qrow + 32 + quad * 8);

    f32x4 O[4];
    #pragma unroll
    for (int mf = 0; mf < 4; ++mf) O[mf] = (f32x4){0.f, 0.f, 0.f, 0.f};
    float m_i = -1e30f, l_i = 0.0f;

    for (int kt = 0; kt <= qt; ++kt) {
        const bool diag = (kt == qt);
        const ushort_t* kp = kb_h + (size_t)(kt * 64) * HD;
        const _Float16* vp = vt_h + kt * 64;

        // S^T: 4 key-fragments x 2 K-chunks, K-frags straight from global.
        f32x4 S[4];
        #pragma unroll
        for (int f = 0; f < 4; ++f) {
            S[f] = (f32x4){0.f, 0.f, 0.f, 0.f};
            if (!diag || f <= sub) {
                const ushort_t* kr = kp + (size_t)(f * 16 + l16) * HD + quad * 8;
                short8 kf0 = *(const short8*)kr;
                short8 kf1 = *(const short8*)(kr + 32);
                S[f] = __builtin_amdgcn_mfma_f32_16x16x32_bf16(kf0, qf0, S[f], 0, 0, 0);
                S[f] = __builtin_amdgcn_mfma_f32_16x16x32_bf16(kf1, qf1, S[f], 0, 0, 0);
            }
        }

        float sc[4][4];
        float cmax = -1e30f;
        #pragma unroll
        for (int f = 0; f < 4; ++f)
            #pragma unroll
            for (int r = 0; r < 4; ++r) {
                float v = S[f][r];
                if (diag && (f * 16 + quad * 4 + r) > rowl) v = -1e30f;
                sc[f][r] = v;
                cmax = fmaxf(cmax, v);
            }
        cmax = fmaxf(cmax, __shfl_xor(cmax, 16));
        cmax = fmaxf(cmax, __shfl_xor(cmax, 32));

        float m_new = fmaxf(m_i, cmax);
        float alpha = __expf(m_i - m_new);
        m_i = m_new;

        float psum = 0.0f;
        #pragma unroll
        for (int f = 0; f < 4; ++f)
            #pragma unroll
            for (int r = 0; r < 4; ++r) {
                float p = __expf(sc[f][r] - m_new);
                sc[f][r] = p;
                psum += p;
            }
        psum += __shfl_xor(psum, 16);
        psum += __shfl_xor(psum, 32);
        l_i = l_i * alpha + psum;

        #pragma unroll
        for (int mf = 0; mf < 4; ++mf)
            #pragma unroll
            for (int r = 0; r < 4; ++r)
                O[mf][r] *= alpha;

        // P^T -> f16 B-fragments (k = quad*4+j == C-layout rows)
        half4 pb[4];
        #pragma unroll
        for (int f = 0; f < 4; ++f)
            #pragma unroll
            for (int j = 0; j < 4; ++j)
                pb[f][j] = (_Float16)sc[f][j];

        // O^T += V^T @ P^T, V-frags straight from global
        #pragma unroll
        for (int mf = 0; mf < 4; ++mf) {
            const _Float16* vb = vp + (size_t)(mf * 16 + l16) * SEQ + quad * 4;
            #pragma unroll
            for (int kc = 0; kc < 4; ++kc) {
                if (!diag || kc <= sub) {
                    half4 va = *(const half4*)(vb + kc * 16);
                    O[mf] = __builtin_amdgcn_mfma_f32_16x16x16f16(va, pb[kc], O[mf], 0, 0, 0);
                }
            }
        }
    }

    float inv = 1.0f / l_i;
    ushort_t* op = abuf + (size_t)(b * SEQ + g * 16 + l16) * HID + h * HD;
    #pragma unroll
    for (int mf = 0; mf < 4; ++mf) {
        short4v st;
        #pragma unroll
        for (int r = 0; r < 4; ++r) st[r] = (short)f2b(O[mf][r] * inv);
        *(short4v*)(op + mf * 16 + quad * 4) = st;
    }
}

// ---------------------------------------------------------------------------
// Kernel 3: output projection via bf16 MFMA (unchanged).
// ---------------------------------------------------------------------------
__global__ __launch_bounds__(256) void oproj_kernel(
    const ushort_t* __restrict__ A, const ushort_t* __restrict__ WoT,
    float* __restrict__ out)
{
    __shared__ ushort_t Asb[128 * LDA];
    __shared__ ushort_t Bsb[64 * LDA];
    const int tid  = threadIdx.x;
    const int w    = tid >> 6;
    const int lane = tid & 63;
    const int quad = lane >> 4;
    const int l16  = lane & 15;
    const int m0 = blockIdx.x * 128;
    const int n0 = blockIdx.y * 64;

    f32x4 acc[2][4];
    #pragma unroll
    for (int mf = 0; mf < 2; ++mf)
        #pragma unroll
        for (int nf = 0; nf < 4; ++nf) acc[mf][nf] = (f32x4){0.f, 0.f, 0.f, 0.f};

    for (int k0 = 0; k0 < HID; k0 += 32) {
        #pragma unroll
        for (int j = 0; j < 2; ++j) {
            int u = tid + j * 256;
            int row = u >> 2, c8 = u & 3;
            *(short8*)&Asb[row * LDA + c8 * 8] =
                *(const short8*)(A + (size_t)(m0 + row) * HID + k0 + c8 * 8);
        }
        {
            int row = tid >> 2, c8 = tid & 3;
            *(short8*)&Bsb[row * LDA + c8 * 8] =
                *(const short8*)(WoT + (size_t)(n0 + row) * HID + k0 + c8 * 8);
        }
        __syncthreads();
        const ushort_t* Ab = &Asb[(w * 32 + l16) * LDA + quad * 8];
        short8 a0 = *(const short8*)Ab;
        short8 a1 = *(const short8*)(Ab + 16 * LDA);
        #pragma unroll
        for (int nf = 0; nf < 4; ++nf) {
            short8 bf = *(const short8*)&Bsb[(nf * 16 + l16) * LDA + quad * 8];
            acc[0][nf] = __builtin_amdgcn_mfma_f32_16x16x32_bf16(a0, bf, acc[0][nf], 0, 0, 0);
            acc[1][nf] = __builtin_amdgcn_mfma_f32_16x16x32_bf16(a1, bf, acc[1][nf], 0, 0, 0);
        }
        __syncthreads();
    }

    #pragma unroll
    for (int mf = 0; mf < 2; ++mf)
        #pragma unroll
        for (int r = 0; r < 4; ++r) {
            size_t rbase = (size_t)(m0 + w * 32 + mf * 16 + quad * 4 + r) * HID + n0;
            #pragma unroll
            for (int f = 0; f < 4; ++f)
                out[rbase + f * 16 + l16] = acc[mf][f][r];
        }
}

extern "C" void kernel_launch(void* const* d_in, const int* in_sizes, int n_in,
                              void* d_out, int out_size, void* d_ws, size_t ws_size,
                              hipStream_t stream) {
    const float* X  = (const float*)d_in[0];
    // d_in[1] = attention_mask: exactly causal; applied analytically.
    const float* Wq = (const float*)d_in[2];
    const float* bq = (const float*)d_in[3];
    const float* Wk = (const float*)d_in[4];
    const float* bk = (const float*)d_in[5];
    const float* Wv = (const float*)d_in[6];
    const float* bv = (const float*)d_in[7];
    const float* Wo = (const float*)d_in[8];
    float* out = (float*)d_out;

    ushort_t* ws    = (ushort_t*)d_ws;
    ushort_t* Xb    = ws;                   // 3,670,016
    ushort_t* WqkvT = Xb    + 3670016;      // 1,032,192
    ushort_t* WoT   = WqkvT + 1032192;      //   802,816
    ushort_t* qbuf  = WoT   + 802816;       // 3,670,016
    ushort_t* kbuf  = qbuf  + 3670016;      //   524,288
    _Float16* vbuf  = (_Float16*)(kbuf + 524288);   //   524,288
    ushort_t* abufb = (ushort_t*)vbuf + 524288;     // 3,670,016

    xcast_kernel<<<dim3(1792), 256, 0, stream>>>(X, Xb);
    wtrans_kernel<<<dim3(28, 28, 4), dim3(32, 8), 0, stream>>>(
        Wq, Wk, Wv, Wo, WqkvT, WoT);
    qkv_kernel<<<dim3(32, 18), 256, 0, stream>>>(
        Xb, WqkvT, bq, bk, bv, qbuf, kbuf, vbuf);
    attn_kernel<<<dim3(128, NH, BATCH), 64, 0, stream>>>(
        qbuf, kbuf, vbuf, abufb);
    oproj_kernel<<<dim3(32, 14), 256, 0, stream>>>(
        abufb, WoT, out);
}

// Round 8
// 207.731 us; speedup vs baseline: 2.0808x; 2.0808x over previous
//
#include <hip/hip_runtime.h>
#include <hip/hip_bf16.h>
#include <math.h>

#define NH 14
#define NKV 2
#define HD 64
#define HID 896
#define SEQ 2048
#define BATCH 2
#define KT 28          // HID / 32

typedef __attribute__((ext_vector_type(8))) short short8;
typedef __attribute__((ext_vector_type(4))) float f32x4;
typedef unsigned short ushort_t;

__device__ __forceinline__ unsigned short f2b(float f) {
    unsigned int u = __float_as_uint(f);
    unsigned int r = (u + 0x7fffu + ((u >> 16) & 1u)) >> 16;   // RNE
    return (unsigned short)r;
}

// ---------------------------------------------------------------------------
// Prep A: X fp32 [4096,896] -> bf16 same layout.
// ---------------------------------------------------------------------------
__global__ __launch_bounds__(256) void xcast_kernel(
    const float* __restrict__ X, ushort_t* __restrict__ Xb)
{
    size_t i = ((size_t)blockIdx.x * 256 + threadIdx.x) * 8;
    float4 a = *(const float4*)(X + i);
    float4 b = *(const float4*)(X + i + 4);
    short8 o;
    o[0] = f2b(a.x); o[1] = f2b(a.y); o[2] = f2b(a.z); o[3] = f2b(a.w);
    o[4] = f2b(b.x); o[5] = f2b(b.y); o[6] = f2b(b.z); o[7] = f2b(b.w);
    *(short8*)(Xb + i) = o;
}

// ---------------------------------------------------------------------------
// Prep B: weight transpose+cast. W [896][N] fp32 -> WT [n][k] bf16.
// ---------------------------------------------------------------------------
__global__ __launch_bounds__(256) void wtrans_kernel(
    const float* __restrict__ Wq, const float* __restrict__ Wk,
    const float* __restrict__ Wv, const float* __restrict__ Wo,
    ushort_t* __restrict__ WqkvT, ushort_t* __restrict__ WoT)
{
    __shared__ float tile[32][33];
    const int tx = threadIdx.x, ty = threadIdx.y;   // block (32,8)
    const int z = blockIdx.z;
    const float* src; ushort_t* dst; int N, rowoff;
    if      (z == 0) { src = Wq; dst = WqkvT; N = HID; rowoff = 0;    }
    else if (z == 1) { src = Wk; dst = WqkvT; N = 128; rowoff = 896;  }
    else if (z == 2) { src = Wv; dst = WqkvT; N = 128; rowoff = 1024; }
    else             { src = Wo; dst = WoT;   N = HID; rowoff = 0;    }
    const int k0 = blockIdx.x * 32;
    const int n0 = blockIdx.y * 32;
    if (n0 >= N) return;
    #pragma unroll
    for (int i = 0; i < 4; ++i)
        tile[ty * 4 + i][tx] = src[(size_t)(k0 + ty * 4 + i) * N + n0 + tx];
    __syncthreads();
    #pragma unroll
    for (int i = 0; i < 4; ++i)
        dst[(size_t)(rowoff + n0 + ty * 4 + i) * HID + k0 + tx]
            = f2b(tile[tx][ty * 4 + i]);
}

// ---------------------------------------------------------------------------
// Kernel 1: QKV GEMM, software-pipelined (double-buffered LDS, register
// prefetch: load k+2 while computing k; ONE barrier per K-step). Tile 128x64.
// Epilogue: bias + RoPE; q bf16, k bf16, V bf16 transposed [d][s].
// ---------------------------------------------------------------------------
#define LDA 40
__global__ __launch_bounds__(256) void qkv_kernel(
    const ushort_t* __restrict__ Xb, const ushort_t* __restrict__ WqkvT,
    const float* __restrict__ bq, const float* __restrict__ bk,
    const float* __restrict__ bv,
    ushort_t* __restrict__ qbuf, ushort_t* __restrict__ kbuf,
    ushort_t* __restrict__ vbuf)
{
    __shared__ ushort_t Asb[2][128 * LDA];
    __shared__ ushort_t Bsb[2][64 * LDA];
    const int tid  = threadIdx.x;
    const int w    = tid >> 6;
    const int lane = tid & 63;
    const int quad = lane >> 4;
    const int l16  = lane & 15;
    const int m0 = blockIdx.x * 128;
    const int nt = blockIdx.y;
    const int nb = nt * 64;

    // staging coords
    const int ar0 = tid >> 2;            // A rows (j=0: 0..63, j=1: +64)
    const int ac8 = tid & 3;
    const ushort_t* Ag0 = Xb + (size_t)(m0 + ar0) * HID + ac8 * 8;
    const ushort_t* Ag1 = Xb + (size_t)(m0 + ar0 + 64) * HID + ac8 * 8;
    const ushort_t* Bg  = WqkvT + (size_t)(nb + ar0) * HID + ac8 * 8;

    f32x4 acc[2][4];
    #pragma unroll
    for (int mf = 0; mf < 2; ++mf)
        #pragma unroll
        for (int nf = 0; nf < 4; ++nf) acc[mf][nf] = (f32x4){0.f, 0.f, 0.f, 0.f};

    short8 aReg0, aReg1, bReg;
    // prologue: load k=0, store buf0, load k=1
    aReg0 = *(const short8*)(Ag0);
    aReg1 = *(const short8*)(Ag1);
    bReg  = *(const short8*)(Bg);
    *(short8*)&Asb[0][ar0 * LDA + ac8 * 8]        = aReg0;
    *(short8*)&Asb[0][(ar0 + 64) * LDA + ac8 * 8] = aReg1;
    *(short8*)&Bsb[0][ar0 * LDA + ac8 * 8]        = bReg;
    aReg0 = *(const short8*)(Ag0 + 32);
    aReg1 = *(const short8*)(Ag1 + 32);
    bReg  = *(const short8*)(Bg  + 32);

    for (int ks = 0; ks < KT; ++ks) {
        __syncthreads();
        const int cur = ks & 1;
        if (ks + 1 < KT) {
            *(short8*)&Asb[cur ^ 1][ar0 * LDA + ac8 * 8]        = aReg0;
            *(short8*)&Asb[cur ^ 1][(ar0 + 64) * LDA + ac8 * 8] = aReg1;
            *(short8*)&Bsb[cur ^ 1][ar0 * LDA + ac8 * 8]        = bReg;
        }
        if (ks + 2 < KT) {
            aReg0 = *(const short8*)(Ag0 + (ks + 2) * 32);
            aReg1 = *(const short8*)(Ag1 + (ks + 2) * 32);
            bReg  = *(const short8*)(Bg  + (ks + 2) * 32);
        }
        const ushort_t* Ab = &Asb[cur][(w * 32 + l16) * LDA + quad * 8];
        short8 a0 = *(const short8*)Ab;
        short8 a1 = *(const short8*)(Ab + 16 * LDA);
        #pragma unroll
        for (int nf = 0; nf < 4; ++nf) {
            short8 bf = *(const short8*)&Bsb[cur][(nf * 16 + l16) * LDA + quad * 8];
            acc[0][nf] = __builtin_amdgcn_mfma_f32_16x16x32_bf16(a0, bf, acc[0][nf], 0, 0, 0);
            acc[1][nf] = __builtin_amdgcn_mfma_f32_16x16x32_bf16(a1, bf, acc[1][nf], 0, 0, 0);
        }
    }

    float bcol[4];
    #pragma unroll
    for (int f = 0; f < 4; ++f) {
        int d = f * 16 + l16;
        bcol[f] = (nt < 14) ? bq[nt * 64 + d]
                : (nt < 16) ? bk[(nt - 14) * 64 + d]
                            : bv[(nt - 16) * 64 + d];
    }
    const float lnth = 13.815510558f;  // ln(1e6)
    float if0 = expf(-((float)l16)        / 32.0f * lnth);
    float if1 = expf(-((float)(l16 + 16)) / 32.0f * lnth);

    #pragma unroll
    for (int mf = 0; mf < 2; ++mf)
        #pragma unroll
        for (int r = 0; r < 4; ++r) {
            int grow = m0 + w * 32 + mf * 16 + quad * 4 + r;
            int b = grow >> 11;
            int s = grow & 2047;
            float v0 = acc[mf][0][r] + bcol[0];
            float v1 = acc[mf][1][r] + bcol[1];
            float v2 = acc[mf][2][r] + bcol[2];
            float v3 = acc[mf][3][r] + bcol[3];
            if (nt < 16) {
                float s0, c0, s1, c1;
                sincosf((float)s * if0, &s0, &c0);
                sincosf((float)s * if1, &s1, &c1);
                float n0 = v0 * c0 - v2 * s0;
                float n2 = v2 * c0 + v0 * s0;
                float n1 = v1 * c1 - v3 * s1;
                float n3 = v3 * c1 + v1 * s1;
                v0 = n0; v1 = n1; v2 = n2; v3 = n3;
            }
            if (nt < 14) {
                ushort_t* dst = qbuf + ((size_t)(b * NH + nt) * SEQ + s) * HD;
                dst[l16]      = f2b(v0);
                dst[l16 + 16] = f2b(v1);
                dst[l16 + 32] = f2b(v2);
                dst[l16 + 48] = f2b(v3);
            } else if (nt < 16) {
                ushort_t* dst = kbuf + ((size_t)(b * NKV + nt - 14) * SEQ + s) * HD;
                dst[l16]      = f2b(v0);
                dst[l16 + 16] = f2b(v1);
                dst[l16 + 32] = f2b(v2);
                dst[l16 + 48] = f2b(v3);
            } else {
                ushort_t* dst = vbuf + (size_t)(b * NKV + nt - 16) * HD * SEQ + s;
                dst[(size_t)(l16)      * SEQ] = f2b(v0);
                dst[(size_t)(l16 + 16) * SEQ] = f2b(v1);
                dst[(size_t)(l16 + 32) * SEQ] = f2b(v2);
                dst[(size_t)(l16 + 48) * SEQ] = f2b(v3);
            }
        }
}

// ---------------------------------------------------------------------------
// Kernel 2: causal flash attention via bf16 MFMA — reverted to the R5
// structure (82 µs best-known): grid (16, NH, B), 4 waves, LDS-staged K/V,
// paired q-tiles (bi, 31-bi). Only change: LDP 72->76 (Ps scatter 4-way ->
// 2-way bank aliasing; quad offsets 0/24/16/8 all distinct).
// ---------------------------------------------------------------------------
#define LDP 76
__global__ __launch_bounds__(256) void attn_kernel(
    const ushort_t* __restrict__ qbuf, const ushort_t* __restrict__ kbuf,
    const ushort_t* __restrict__ vbuf, ushort_t* __restrict__ abuf)
{
    __shared__ ushort_t Ks[64 * LDP];
    __shared__ ushort_t Vt[64 * LDP];
    __shared__ ushort_t Ps[4][16 * LDP];

    const int tid  = threadIdx.x;
    const int w    = tid >> 6;
    const int lane = tid & 63;
    const int quad = lane >> 4;
    const int l16  = lane & 15;
    const int bi = blockIdx.x;
    const int h  = blockIdx.y;
    const int b  = blockIdx.z;
    const int kvh = h / (NH / NKV);

    const ushort_t* kb_h = kbuf + (size_t)(b * NKV + kvh) * SEQ * HD;
    const ushort_t* vt_h = vbuf + (size_t)(b * NKV + kvh) * HD * SEQ;

    for (int pass = 0; pass < 2; ++pass) {
        const int qt = pass ? (31 - bi) : bi;

        const ushort_t* qrow =
            qbuf + ((size_t)((b * NH + h) * SEQ) + qt * 64 + w * 16 + l16) * HD;
        short8 qf0 = *(const short8*)(qrow + quad * 8);
        short8 qf1 = *(const short8*)(qrow + 32 + quad * 8);

        f32x4 O[4];
        float m_i[4], l_i[4];
        #pragma unroll
        for (int n = 0; n < 4; ++n) O[n] = (f32x4){0.f, 0.f, 0.f, 0.f};
        #pragma unroll
        for (int r = 0; r < 4; ++r) { m_i[r] = -1e30f; l_i[r] = 0.0f; }

        for (int kt = 0; kt <= qt; ++kt) {
            __syncthreads();
            for (int i = tid; i < 512; i += 256) {
                int row = i >> 3, c8 = i & 7;
                *(short8*)&Ks[row * LDP + c8 * 8] =
                    *(const short8*)(kb_h + ((size_t)(kt * 64 + row)) * HD + c8 * 8);
                *(short8*)&Vt[row * LDP + c8 * 8] =
                    *(const short8*)(vt_h + (size_t)row * SEQ + kt * 64 + c8 * 8);
            }
            __syncthreads();

            f32x4 S[4];
            #pragma unroll
            for (int f = 0; f < 4; ++f) {
                S[f] = (f32x4){0.f, 0.f, 0.f, 0.f};
                short8 kf0 = *(const short8*)&Ks[(f * 16 + l16) * LDP + quad * 8];
                short8 kf1 = *(const short8*)&Ks[(f * 16 + l16) * LDP + 32 + quad * 8];
                S[f] = __builtin_amdgcn_mfma_f32_16x16x32_bf16(qf0, kf0, S[f], 0, 0, 0);
                S[f] = __builtin_amdgcn_mfma_f32_16x16x32_bf16(qf1, kf1, S[f], 0, 0, 0);
            }

            const bool diag = (kt == qt);
            float sc[4][4];
            #pragma unroll
            for (int f = 0; f < 4; ++f)
                #pragma unroll
                for (int r = 0; r < 4; ++r) {
                    float v = S[f][r] * 0.125f;
                    if (diag && (f * 16 + l16) > (w * 16 + quad * 4 + r)) v = -1e30f;
                    sc[f][r] = v;
                }

            float pm[4];
            #pragma unroll
            for (int r = 0; r < 4; ++r)
                pm[r] = fmaxf(fmaxf(sc[0][r], sc[1][r]), fmaxf(sc[2][r], sc[3][r]));
            #pragma unroll
            for (int off = 1; off < 16; off <<= 1)
                #pragma unroll
                for (int r = 0; r < 4; ++r)
                    pm[r] = fmaxf(pm[r], __shfl_xor(pm[r], off));

            float alpha[4], psum[4];
            #pragma unroll
            for (int r = 0; r < 4; ++r) {
                float mnew = fmaxf(m_i[r], pm[r]);
                alpha[r] = __expf(m_i[r] - mnew);
                m_i[r] = mnew;
                psum[r] = 0.0f;
            }
            #pragma unroll
            for (int f = 0; f < 4; ++f)
                #pragma unroll
                for (int r = 0; r < 4; ++r) {
                    float p = __expf(sc[f][r] - m_i[r]);
                    sc[f][r] = p;
                    psum[r] += p;
                }
            #pragma unroll
            for (int off = 1; off < 16; off <<= 1)
                #pragma unroll
                for (int r = 0; r < 4; ++r)
                    psum[r] += __shfl_xor(psum[r], off);
            #pragma unroll
            for (int r = 0; r < 4; ++r)
                l_i[r] = l_i[r] * alpha[r] + psum[r];
            #pragma unroll
            for (int n = 0; n < 4; ++n)
                #pragma unroll
                for (int r = 0; r < 4; ++r)
                    O[n][r] *= alpha[r];

            #pragma unroll
            for (int f = 0; f < 4; ++f)
                #pragma unroll
                for (int r = 0; r < 4; ++r)
                    Ps[w][(quad * 4 + r) * LDP + f * 16 + l16] = f2b(sc[f][r]);
            short8 pa0 = *(const short8*)&Ps[w][l16 * LDP + quad * 8];
            short8 pa1 = *(const short8*)&Ps[w][l16 * LDP + 32 + quad * 8];

            #pragma unroll
            for (int n = 0; n < 4; ++n) {
                short8 vf0 = *(const short8*)&Vt[(n * 16 + l16) * LDP + quad * 8];
                short8 vf1 = *(const short8*)&Vt[(n * 16 + l16) * LDP + 32 + quad * 8];
                O[n] = __builtin_amdgcn_mfma_f32_16x16x32_bf16(pa0, vf0, O[n], 0, 0, 0);
                O[n] = __builtin_amdgcn_mfma_f32_16x16x32_bf16(pa1, vf1, O[n], 0, 0, 0);
            }
        }

        float inv[4];
        #pragma unroll
        for (int r = 0; r < 4; ++r) inv[r] = 1.0f / l_i[r];
        #pragma unroll
        for (int n = 0; n < 4; ++n)
            #pragma unroll
            for (int r = 0; r < 4; ++r) {
                int rowg = qt * 64 + w * 16 + quad * 4 + r;
                abuf[(size_t)(b * SEQ + rowg) * HID + h * HD + n * 16 + l16]
                    = f2b(O[n][r] * inv[r]);
            }
    }
}

// ---------------------------------------------------------------------------
// Kernel 3: output projection, same pipelined GEMM. abuf bf16 @ WoT -> fp32.
// ---------------------------------------------------------------------------
__global__ __launch_bounds__(256) void oproj_kernel(
    const ushort_t* __restrict__ A, const ushort_t* __restrict__ WoT,
    float* __restrict__ out)
{
    __shared__ ushort_t Asb[2][128 * LDA];
    __shared__ ushort_t Bsb[2][64 * LDA];
    const int tid  = threadIdx.x;
    const int w    = tid >> 6;
    const int lane = tid & 63;
    const int quad = lane >> 4;
    const int l16  = lane & 15;
    const int m0 = blockIdx.x * 128;
    const int n0 = blockIdx.y * 64;

    const int ar0 = tid >> 2;
    const int ac8 = tid & 3;
    const ushort_t* Ag0 = A + (size_t)(m0 + ar0) * HID + ac8 * 8;
    const ushort_t* Ag1 = A + (size_t)(m0 + ar0 + 64) * HID + ac8 * 8;
    const ushort_t* Bg  = WoT + (size_t)(n0 + ar0) * HID + ac8 * 8;

    f32x4 acc[2][4];
    #pragma unroll
    for (int mf = 0; mf < 2; ++mf)
        #pragma unroll
        for (int nf = 0; nf < 4; ++nf) acc[mf][nf] = (f32x4){0.f, 0.f, 0.f, 0.f};

    short8 aReg0, aReg1, bReg;
    aReg0 = *(const short8*)(Ag0);
    aReg1 = *(const short8*)(Ag1);
    bReg  = *(const short8*)(Bg);
    *(short8*)&Asb[0][ar0 * LDA + ac8 * 8]        = aReg0;
    *(short8*)&Asb[0][(ar0 + 64) * LDA + ac8 * 8] = aReg1;
    *(short8*)&Bsb[0][ar0 * LDA + ac8 * 8]        = bReg;
    aReg0 = *(const short8*)(Ag0 + 32);
    aReg1 = *(const short8*)(Ag1 + 32);
    bReg  = *(const short8*)(Bg  + 32);

    for (int ks = 0; ks < KT; ++ks) {
        __syncthreads();
        const int cur = ks & 1;
        if (ks + 1 < KT) {
            *(short8*)&Asb[cur ^ 1][ar0 * LDA + ac8 * 8]        = aReg0;
            *(short8*)&Asb[cur ^ 1][(ar0 + 64) * LDA + ac8 * 8] = aReg1;
            *(short8*)&Bsb[cur ^ 1][ar0 * LDA + ac8 * 8]        = bReg;
        }
        if (ks + 2 < KT) {
            aReg0 = *(const short8*)(Ag0 + (ks + 2) * 32);
            aReg1 = *(const short8*)(Ag1 + (ks + 2) * 32);
            bReg  = *(const short8*)(Bg  + (ks + 2) * 32);
        }
        const ushort_t* Ab = &Asb[cur][(w * 32 + l16) * LDA + quad * 8];
        short8 a0 = *(const short8*)Ab;
        short8 a1 = *(const short8*)(Ab + 16 * LDA);
        #pragma unroll
        for (int nf = 0; nf < 4; ++nf) {
            short8 bf = *(const short8*)&Bsb[cur][(nf * 16 + l16) * LDA + quad * 8];
            acc[0][nf] = __builtin_amdgcn_mfma_f32_16x16x32_bf16(a0, bf, acc[0][nf], 0, 0, 0);
            acc[1][nf] = __builtin_amdgcn_mfma_f32_16x16x32_bf16(a1, bf, acc[1][nf], 0, 0, 0);
        }
    }

    #pragma unroll
    for (int mf = 0; mf < 2; ++mf)
        #pragma unroll
        for (int r = 0; r < 4; ++r) {
            size_t rbase = (size_t)(m0 + w * 32 + mf * 16 + quad * 4 + r) * HID + n0;
            #pragma unroll
            for (int f = 0; f < 4; ++f)
                out[rbase + f * 16 + l16] = acc[mf][f][r];
        }
}

extern "C" void kernel_launch(void* const* d_in, const int* in_sizes, int n_in,
                              void* d_out, int out_size, void* d_ws, size_t ws_size,
                              hipStream_t stream) {
    const float* X  = (const float*)d_in[0];
    // d_in[1] = attention_mask: exactly causal; applied analytically.
    const float* Wq = (const float*)d_in[2];
    const float* bq = (const float*)d_in[3];
    const float* Wk = (const float*)d_in[4];
    const float* bk = (const float*)d_in[5];
    const float* Wv = (const float*)d_in[6];
    const float* bv = (const float*)d_in[7];
    const float* Wo = (const float*)d_in[8];
    float* out = (float*)d_out;

    ushort_t* ws    = (ushort_t*)d_ws;
    ushort_t* Xb    = ws;                   // 3,670,016
    ushort_t* WqkvT = Xb    + 3670016;      // 1,032,192
    ushort_t* WoT   = WqkvT + 1032192;      //   802,816
    ushort_t* qbuf  = WoT   + 802816;       // 3,670,016
    ushort_t* kbuf  = qbuf  + 3670016;      //   524,288
    ushort_t* vbuf  = kbuf  + 524288;       //   524,288
    ushort_t* abufb = vbuf  + 524288;       // 3,670,016

    xcast_kernel<<<dim3(1792), 256, 0, stream>>>(X, Xb);
    wtrans_kernel<<<dim3(28, 28, 4), dim3(32, 8), 0, stream>>>(
        Wq, Wk, Wv, Wo, WqkvT, WoT);
    qkv_kernel<<<dim3(32, 18), 256, 0, stream>>>(
        Xb, WqkvT, bq, bk, bv, qbuf, kbuf, vbuf);
    attn_kernel<<<dim3(16, NH, BATCH), 256, 0, stream>>>(
        qbuf, kbuf, vbuf, abufb);
    oproj_kernel<<<dim3(32, 14), 256, 0, stream>>>(
        abufb, WoT, out);
}